// Round 24
// baseline (396.960 us; speedup 1.0000x reference)
//
#include <hip/hip_runtime.h>
#include <stdint.h>

#define BATCH 512
#define MAXZ 3

typedef int v4i __attribute__((ext_vector_type(4)));
typedef float f2 __attribute__((ext_vector_type(2)));

// ---- workspace layout (bytes) ----
static const size_t OFF_W2F  = 0;          // 50*8*64*16 i8 B-frags = 409600
static const size_t OFF_W3P  = 409600;     // 9*128*4 u32
static const size_t OFF_W4P  = 428032;
static const size_t OFF_FCP  = 446464;     // 64*512 u32
static const size_t OFF_STAT = 577536;     // zcnt@8192; zlist@10240
static const size_t OFF_CSUM = 839680;     // 512*128 f32
static const size_t OFF_B1P  = 1101824;    // 512*784*16
static const size_t OFF_H2   = 7524352;    // 512*144*128*2 u16
static const size_t OFF_B2P  = 26398720;   // 512*144*16
static const size_t OFF_W1P  = 27578368;   // 128*28 f32 (row stride 112B, 16B-aligned)
// end ~27.6 MB

// Numerics model (validated, absmax=0): conv1 = np.einsum f32 SSE2 order;
// means = numpy pairwise-f32 (leaf geometry + adjacent-pair tree); conv2 =
// i8 MFMA with act in {-1,0,+1}; layers 3/4 exact integer xnor-popcount.
//
// bconv2: r19 structure FINAL (104.4us). DO NOT PERTURB.
// r25 pack-parallel -115us. r26/27 fusion -46us. r32/33 csum de-spill
// -38us. r35/36 w1p float4 rows -8.6us. r37 packed-f32 einsum -5.9us
// (382.1 best).
// r38: tail_fused 256 -> 512 threads. Grid is fixed at 512 blocks (per-
// sample chain) => occupancy was GRID-limited: 2 blocks/CU x 2 waves =
// 4 waves/CU through 5 serial latency-bound phases. 512 threads => 16
// waves/CU. Work redistribution is mechanical (stride-4 position loops,
// NT template in npmean); every output written exactly once, identical
// values => bit-exact.

__device__ inline float mulr(float a, float b) {
    float t = a * b;
    asm volatile("" : "+v"(t));
    return t;
}

__device__ inline f2 mkf2(float a, float b) { f2 r; r.x = a; r.y = b; return r; }

__device__ inline void xp4(int& acc, uint4 a, uint4 b) {
    acc += __popc(a.x ^ b.x);
    acc += __popc(a.y ^ b.y);
    acc += __popc(a.z ^ b.z);
    acc += __popc(a.w ^ b.w);
}

// Packed-pair einsum on a register patch array (csum path).
// Component-wise identical op order to the validated scalar einsum25.
__device__ inline float einsum25k(const float* __restrict__ patch,
                                  const float* __restrict__ wr) {
#pragma clang fp contract(off)
    f2 l01 = mkf2(wr[0], wr[1]) * mkf2(patch[0], patch[1]);
    f2 l23 = mkf2(wr[2], wr[3]) * mkf2(patch[2], patch[3]);
#pragma unroll
    for (int t = 1; t < 6; ++t) {
        l01 += mkf2(wr[4 * t + 0], wr[4 * t + 1]) * mkf2(patch[4 * t + 0], patch[4 * t + 1]);
        l23 += mkf2(wr[4 * t + 2], wr[4 * t + 3]) * mkf2(patch[4 * t + 2], patch[4 * t + 3]);
    }
    float acc = (l01.x + l01.y) + (l23.x + l23.y);
    acc += wr[24] * patch[24];
    return acc > 0.f ? acc : 0.f;
}

// Packed-pair einsum on 25 named scalars + float4 weight loads from the
// padded 16B-aligned w1p row (bin path). Component-wise identical op
// order => bit-exact.
__device__ inline float einsum25pk(
    float p0, float p1, float p2, float p3, float p4,
    float p5, float p6, float p7, float p8, float p9,
    float p10, float p11, float p12, float p13, float p14,
    float p15, float p16, float p17, float p18, float p19,
    float p20, float p21, float p22, float p23, float p24,
    const float* __restrict__ wr) {
#pragma clang fp contract(off)
    float4 wa = *(const float4*)(wr + 0);
    float4 wb = *(const float4*)(wr + 4);
    float4 wc = *(const float4*)(wr + 8);
    float4 wd = *(const float4*)(wr + 12);
    float4 we = *(const float4*)(wr + 16);
    float4 wf = *(const float4*)(wr + 20);
    float w24 = wr[24];
    f2 l01 = mkf2(wa.x, wa.y) * mkf2(p0, p1);
    f2 l23 = mkf2(wa.z, wa.w) * mkf2(p2, p3);
    l01 += mkf2(wb.x, wb.y) * mkf2(p4, p5);
    l23 += mkf2(wb.z, wb.w) * mkf2(p6, p7);
    l01 += mkf2(wc.x, wc.y) * mkf2(p8, p9);
    l23 += mkf2(wc.z, wc.w) * mkf2(p10, p11);
    l01 += mkf2(wd.x, wd.y) * mkf2(p12, p13);
    l23 += mkf2(wd.z, wd.w) * mkf2(p14, p15);
    l01 += mkf2(we.x, we.y) * mkf2(p16, p17);
    l23 += mkf2(we.z, we.w) * mkf2(p18, p19);
    l01 += mkf2(wf.x, wf.y) * mkf2(p20, p21);
    l23 += mkf2(wf.z, wf.w) * mkf2(p22, p23);
    float acc = (l01.x + l01.y) + (l23.x + l23.y);
    acc += w24 * p24;
    return acc > 0.f ? acc : 0.f;
}

// ---- shared npmean+binarize math on LDS-resident u16 counts ----
// NT = block size (stride for tree/binarize loops). Leaf phase and
// MODE-1 phase mask by absolute tid => identical math at any NT.
template <int NT, int NPOS, int NLEAF, int CHUNK, int L0, int L1, int MODE>
__device__ inline void npmean_bin_dev(const uint32_t* sh, float* ls,
                                      const float* __restrict__ alpha,
                                      uint32_t* dst, int tid) {
    const int NTOT = NPOS * 128;
    if (tid < NLEAF) {
        int j0 = CHUNK * (tid >> 1) + ((tid & 1) ? L0 : 0);
        int len = (tid & 1) ? L1 : L0;
        float r[8];
#pragma unroll
        for (int k = 0; k < 8; ++k) {
            int j = j0 + k;
            int c = j / NPOS, p = j - c * NPOS;
            int e = p * 128 + c;
            uint32_t w = sh[e >> 1];
            float fv = (float)((e & 1) ? (w >> 16) : (w & 0xffffu));
            r[k] = mulr(alpha[c], fv);
        }
        int i = 8;
        int lim = len - (len % 8);
        for (; i < lim; i += 8) {
#pragma unroll
            for (int k = 0; k < 8; ++k) {
                int j = j0 + i + k;
                int c = j / NPOS, p = j - c * NPOS;
                int e = p * 128 + c;
                uint32_t w = sh[e >> 1];
                float fv = (float)((e & 1) ? (w >> 16) : (w & 0xffffu));
                r[k] += mulr(alpha[c], fv);
            }
        }
        float res = ((r[0] + r[1]) + (r[2] + r[3])) + ((r[4] + r[5]) + (r[6] + r[7]));
        for (; i < len; ++i) {
            int j = j0 + i;
            int c = j / NPOS, p = j - c * NPOS;
            int e = p * 128 + c;
            uint32_t w = sh[e >> 1];
            float fv = (float)((e & 1) ? (w >> 16) : (w & 0xffffu));
            res += mulr(alpha[c], fv);
        }
        ls[tid] = res;
    }
    __syncthreads();
    int src = 0, cnt = NLEAF;
    while (cnt > 1) {
        int dst2 = src + cnt;
        for (int i = tid; i < cnt / 2; i += NT) ls[dst2 + i] = ls[src + 2 * i] + ls[src + 2 * i + 1];
        __syncthreads();
        src = dst2; cnt >>= 1;
    }
    float mean = ls[src] / (float)NTOT;
    if (MODE == 0) {
        for (int widx = tid; widx < NPOS * 4; widx += NT) {
            int w = widx & 3;
            uint32_t bits = 0;
#pragma unroll
            for (int i = 0; i < 32; i += 2) {
                uint32_t pw = sh[widx * 16 + (i >> 1)];
                float v0 = mulr(alpha[w * 32 + i], (float)(pw & 0xffffu));
                float v1 = mulr(alpha[w * 32 + i + 1], (float)(pw >> 16));
                bits |= (v0 > mean ? 1u : 0u) << i;
                bits |= (v1 > mean ? 1u : 0u) << (i + 1);
            }
            dst[widx] = bits;
        }
    } else {
        if (tid < 64) {
            int w = tid;
            uint32_t bits = 0;
#pragma unroll
            for (int i = 0; i < 32; ++i) {
                int f = w * 32 + i;
                int c = f >> 4, sp = f & 15;
                int e = sp * 128 + c;
                uint32_t pw = sh[e >> 1];
                float v = mulr(alpha[c], (float)((e & 1) ? (pw >> 16) : (pw & 0xffffu)));
                bits |= (v > mean ? 1u : 0u) << i;
            }
            dst[w] = bits;
        }
    }
}

// ---------------- conv1 channel sums + (absorbed) weight packing ----------
// launch_bounds(256,2) => VGPR ceiling 256: wreg[4][25]+patch[25] resident.
__global__ __launch_bounds__(256, 2) void conv1_csum_pack(
    const float* __restrict__ x, const float* __restrict__ w1,
    float* __restrict__ csum,
    const float* __restrict__ w2, uint32_t* __restrict__ b2f,
    const float* __restrict__ w3, const float* __restrict__ w4,
    uint32_t* __restrict__ w3p, uint32_t* __restrict__ w4p,
    const float* __restrict__ wfc, uint32_t* __restrict__ fcp,
    int* __restrict__ zcnt, float* __restrict__ w1p) {
    __shared__ float img[32 * 36];
    int blk = blockIdx.x;
    int tid = threadIdx.x;
    if (blk >= 4096) {
        int idx = (blk - 4096) * 256 + tid;
        if (idx < 102400) {
            int d = idx;
            int j4 = d & 3;
            int lane = (d >> 2) & 63;
            int ok = d >> 8;
            int octile = ok & 7, kstep = ok >> 3;
            int oc = octile * 16 + (lane & 15);
            uint32_t dv = 0;
#pragma unroll
            for (int jj = 0; jj < 4; ++jj) {
                int j = j4 * 4 + jj;
                int k = kstep * 64 + (lane >> 4) * 16 + j;
                int tap = k >> 7, ch = k & 127;
                uint32_t byte = (w2[(size_t)(oc * 128 + ch) * 25 + tap] > 0.f) ? 0x01u : 0xFFu;
                dv |= byte << (8 * jj);
            }
            b2f[d] = dv;
        } else if (idx < 104704) {
            int id2 = idx - 102400;
            const float* w = (id2 < 1152) ? w3 : w4;
            uint32_t* wp = (id2 < 1152) ? w3p : w4p;
            int id3 = (id2 < 1152) ? id2 : id2 - 1152;
            int oc = id3 / 9, t = id3 - oc * 9;
            uint32_t words[4] = {0u, 0u, 0u, 0u};
            for (int ic = 0; ic < 128; ++ic) {
                float v = w[(size_t)(oc * 128 + ic) * 9 + t];
                if (v > 0.f) words[ic >> 5] |= 1u << (ic & 31);
            }
#pragma unroll
            for (int k = 0; k < 4; ++k) wp[((size_t)t * 128 + oc) * 4 + k] = words[k];
        } else if (idx < 137472) {
            int id2 = idx - 104704;
            int o = id2 >> 6, k = id2 & 63;
            uint32_t bits = 0;
#pragma unroll
            for (int i = 0; i < 32; ++i)
                bits |= (wfc[(size_t)o * 2048 + k * 32 + i] > 0.f ? 1u : 0u) << i;
            fcp[k * 512 + o] = bits;
        } else if (idx < 137984) {
            zcnt[idx - 137472] = 0;
        } else if (idx < 141568) {
            // w1 -> padded w1p[128][28]: row stride 112B (16B-aligned)
            int e = idx - 137984;
            int c = e / 28, t = e - c * 28;
            w1p[e] = (t < 25) ? w1[c * 25 + t] : 0.f;
        }
        return;
    }
    int n = blk >> 3, g = blk & 7;
    for (int i = tid; i < 1024; i += 256) {
        int y = i >> 5, xx = i & 31;
        img[y * 36 + xx] = x[(size_t)n * 1024 + i];
    }
    __syncthreads();
    int wave = tid >> 6, lane = tid & 63;
    int seg = lane >> 3, k = lane & 7;
    int soff = seg * 96 + (seg >= 4 ? 8 : 0);
    int strips = ((seg & 3) == 3) ? 13 : 12;
    int c0 = g * 16 + wave * 4;
    float wreg[4][25];
#pragma unroll
    for (int it = 0; it < 4; ++it)
#pragma unroll
        for (int t = 0; t < 25; ++t) wreg[it][t] = w1[(c0 + it) * 25 + t];
    float racc[4];
    for (int i = 0; i < strips; ++i) {
        int p = soff + 8 * i + k;
        int y = p / 28, xx = p - y * 28;
        const float* ib = &img[y * 36 + xx];
        float patch[25];
#pragma unroll
        for (int ky = 0; ky < 5; ++ky)
#pragma unroll
            for (int kx = 0; kx < 5; ++kx)
                patch[ky * 5 + kx] = ib[ky * 36 + kx];
#pragma unroll
        for (int it = 0; it < 4; ++it) {
            float h = einsum25k(patch, wreg[it]);
            racc[it] = (i == 0) ? h : racc[it] + h;
        }
    }
#pragma unroll
    for (int it = 0; it < 4; ++it) {
        float r = racc[it];
        r = r + __shfl_xor(r, 1);
        r = r + __shfl_xor(r, 2);
        r = r + __shfl_xor(r, 4);   // leaf sum
        r = r + __shfl_xor(r, 8);
        r = r + __shfl_xor(r, 16);
        r = r + __shfl_xor(r, 32);  // channel sum
        if (lane == 0) csum[n * 128 + c0 + it] = r;
    }
}

// ---------------- conv1 binarize + pack (tree folded in); grid (n, q) -----
// Weights from padded w1p rows via float4; packed-f32 einsum.
__global__ __launch_bounds__(256) void conv1_bin(
    const float* __restrict__ x, const float* __restrict__ w1p,
    const float* __restrict__ csum, uint32_t* __restrict__ b1p,
    int* __restrict__ zcnt, int* __restrict__ zlist) {
    __shared__ float img[32 * 36];
    __shared__ float tree[256];
    int blk = blockIdx.x;
    int n = blk >> 2, q = blk & 3;
    int tid = threadIdx.x;
    for (int i = tid; i < 1024; i += 256) {
        int y = i >> 5, xx = i & 31;
        img[y * 36 + xx] = x[(size_t)n * 1024 + i];
    }
    if (tid < 128) tree[tid] = csum[n * 128 + tid];
    __syncthreads();
    int src = 0, cnt = 128;
    while (cnt > 1) {
        int dst = src + cnt;
        for (int i = tid; i < cnt / 2; i += 256) tree[dst + i] = tree[src + 2 * i] + tree[src + 2 * i + 1];
        __syncthreads();
        src = dst; cnt >>= 1;
    }
    float mean = tree[src] / 100352.0f;
    int p = q * 256 + tid;
    if (p < 784) {
        int y = p / 28, xx = p - y * 28;
        const float* ib = &img[y * 36 + xx];
        float p0  = ib[0],   p1  = ib[1],   p2  = ib[2],   p3  = ib[3],   p4  = ib[4];
        float p5  = ib[36],  p6  = ib[37],  p7  = ib[38],  p8  = ib[39],  p9  = ib[40];
        float p10 = ib[72],  p11 = ib[73],  p12 = ib[74],  p13 = ib[75],  p14 = ib[76];
        float p15 = ib[108], p16 = ib[109], p17 = ib[110], p18 = ib[111], p19 = ib[112];
        float p20 = ib[144], p21 = ib[145], p22 = ib[146], p23 = ib[147], p24 = ib[148];
        uint32_t words[4] = {0u, 0u, 0u, 0u};
#pragma unroll 2
        for (int c = 0; c < 128; ++c) {
            float h = einsum25pk(p0, p1, p2, p3, p4, p5, p6, p7, p8, p9,
                                 p10, p11, p12, p13, p14, p15, p16, p17, p18, p19,
                                 p20, p21, p22, p23, p24, w1p + c * 28);
            if (h > mean) words[c >> 5] |= 1u << (c & 31);
            else if (h == mean) {
                int kz = atomicAdd(&zcnt[n], 1);
                if (kz < MAXZ) zlist[n * MAXZ + kz] = p * 128 + c;
            }
        }
#pragma unroll
        for (int k = 0; k < 4; ++k) b1p[((size_t)n * 784 + p) * 4 + k] = words[k];
    }
}

// ---------------- bconv2 via i8 MFMA (r19 FINAL — do not perturb) ----------
__global__ __launch_bounds__(256) void bconv2_mfma(
    const uint32_t* __restrict__ b1p, const uint8_t* __restrict__ b2f,
    uint16_t* __restrict__ rout, const int* __restrict__ zcnt,
    const int* __restrict__ zlist) {
    __shared__ __align__(16) uint32_t acts32[7168];   // 8*28*128 i8 = 28672 B
    uint8_t* acts = (uint8_t*)acts32;
    int blk = blockIdx.x;
    int n = blk / 6, r = blk - n * 6;
    int tid = threadIdx.x;
    const uint32_t* bsrc = b1p + ((size_t)n * 784 + 4 * r * 28) * 4;
    for (int d = tid; d < 7168; d += 256) {
        int pos = d >> 5;
        int nibidx = d & 31;
        uint32_t word = bsrc[pos * 4 + (nibidx >> 3)];
        uint32_t nib = (word >> ((nibidx & 7) * 4)) & 0xF;
        uint32_t spread = (nib * 0x00204081u) & 0x01010101u;
        int dsw = d ^ ((pos & 7) << 2);                // swizzled dword index
        acts32[dsw] = ~(spread * 0xFEu);
    }
    __syncthreads();
    if (tid == 0) {
        int nz = zcnt[n]; nz = nz > MAXZ ? MAXZ : nz;
        for (int i = 0; i < nz; ++i) {
            int e = zlist[n * MAXZ + i];
            int p = e >> 7, zc = e & 127;
            int zy = p / 28, zx = p - zy * 28;
            int ry = zy - 4 * r;
            if (ry >= 0 && ry < 8) {
                int ba = ((ry * 28 + zx) * 128 + zc);
                ba ^= ((ba >> 7) & 7) << 4;
                acts[ba] = 0;
            }
        }
    }
    __syncthreads();

    int lane = tid & 63, w = tid >> 6;
    int rr = w >> 1, oh = w & 1;
    int ml = lane & 15, khi = lane >> 4;
    int pairl = ml >> 2, dy = (ml >> 1) & 1, dx = ml & 1;
    int abase[3];
#pragma unroll
    for (int t = 0; t < 3; ++t) {
        int px = 2 * (4 * t + pairl) + dx;
        abase[t] = ((dy + 2 * rr) * 28 + px) * 128 + khi * 16;
    }
    const uint8_t* bp = b2f + (size_t)(oh * 4096 + lane * 16);
    v4i c[3][4] = {};
#pragma unroll 2
    for (int kstep = 0; kstep < 50; ++kstep) {
        int tap = kstep >> 1;
        int ky = tap / 5, kx = tap - ky * 5;
        int koff = (ky * 28 + kx) * 128 + (kstep & 1) * 64;
        int a0a = abase[0] + koff; a0a ^= ((a0a >> 7) & 7) << 4;
        int a1a = abase[1] + koff; a1a ^= ((a1a >> 7) & 7) << 4;
        int a2a = abase[2] + koff; a2a ^= ((a2a >> 7) & 7) << 4;
        v4i a0 = *(const v4i*)(acts + a0a);
        v4i a1 = *(const v4i*)(acts + a1a);
        v4i a2 = *(const v4i*)(acts + a2a);
        const uint8_t* bk = bp + kstep * 8192;
#pragma unroll
        for (int o = 0; o < 4; ++o) {
            v4i b = *(const v4i*)(bk + o * 1024);
            c[0][o] = __builtin_amdgcn_mfma_i32_16x16x64_i8(a0, b, c[0][o], 0, 0, 0);
            c[1][o] = __builtin_amdgcn_mfma_i32_16x16x64_i8(a1, b, c[1][o], 0, 0, 0);
            c[2][o] = __builtin_amdgcn_mfma_i32_16x16x64_i8(a2, b, c[2][o], 0, 0, 0);
        }
    }
    uint16_t* outb = rout + ((size_t)n * 144 + (2 * r + rr) * 12) * 128;
#pragma unroll
    for (int t = 0; t < 3; ++t) {
#pragma unroll
        for (int o = 0; o < 4; ++o) {
            v4i cc = c[t][o];
            int m = max(max(cc.x, cc.y), max(cc.z, cc.w));
            m = m > 0 ? m : 0;
            outb[(4 * t + khi) * 128 + (4 * oh + o) * 16 + ml] = (uint16_t)m;
        }
    }
}

// ---------------- npmean144: h2 -> b2p ----------------
__global__ __launch_bounds__(256) void npmean144_kernel(
    const uint16_t* __restrict__ rbuf, const float* __restrict__ alpha,
    uint32_t* __restrict__ bp) {
    __shared__ uint32_t sh[144 * 64];
    __shared__ float ls[2 * 256];
    int n = blockIdx.x, tid = threadIdx.x;
    const uint32_t* rb32 = (const uint32_t*)(rbuf + (size_t)n * 144 * 128);
    for (int i = tid; i < 144 * 64; i += 256) sh[i] = rb32[i];
    __syncthreads();
    npmean_bin_dev<256, 144, 256, 144, 72, 72, 0>(sh, ls, alpha, bp + (size_t)n * 576, tid);
}

// ---------------- tail_fused: bconv3+npmean100+bconv4+npmean16+fc ---------
// r38: 512 threads (8 waves/block) — grid fixed at 512 blocks, so TLP was
// grid-limited at 4 waves/CU; now 16 waves/CU. Work redistributed over
// s in {0..3}; every output written exactly once => bit-exact.
__global__ __launch_bounds__(512) void tail_fused(
    const uint32_t* __restrict__ b2p,
    const uint32_t* __restrict__ w3p, const float* __restrict__ a3,
    const uint32_t* __restrict__ w4p, const float* __restrict__ a4,
    const uint32_t* __restrict__ fcpT, const float* __restrict__ bfc,
    const float* __restrict__ afc, float* __restrict__ out) {
    __shared__ __align__(16) uint32_t act[576];
    __shared__ __align__(16) uint16_t h3s[100 * 128];   // 25.6 KB
    __shared__ float ls[2 * 128];
    __shared__ __align__(16) uint32_t b3s[400];
    __shared__ __align__(16) uint16_t h4s[16 * 128];
    __shared__ uint32_t bxs[64];
    int n = blockIdx.x, tid = threadIdx.x;
    int oc = tid & 127, s = tid >> 7;   // s in {0,1,2,3}

    // ---- bconv3: 12x12 -> 10x10 ----
    const uint32_t* src = b2p + (size_t)n * 576;
    for (int i = tid; i < 576; i += 512) act[i] = src[i];
    {
        uint4 wreg[9];
#pragma unroll
        for (int t = 0; t < 9; ++t) wreg[t] = *(const uint4*)&w3p[(t * 128 + oc) * 4];
        __syncthreads();
        for (int pp = s; pp < 100; pp += 4) {
            int py = pp / 10, px = pp - py * 10;
            int acc = 0;
#pragma unroll
            for (int rr = 0; rr < 3; ++rr)
#pragma unroll
                for (int kx = 0; kx < 3; ++kx)
                    xp4(acc, *(const uint4*)&act[((py + rr) * 12 + px + kx) * 4], wreg[rr * 3 + kx]);
            int r = 1152 - 2 * acc;
            r = r > 0 ? r : 0;
            h3s[pp * 128 + oc] = (uint16_t)r;
        }
    }
    __syncthreads();

    // ---- npmean100 + binarize -> b3s ----
    npmean_bin_dev<512, 100, 128, 200, 96, 104, 0>((const uint32_t*)h3s, ls, a3, b3s, tid);
    __syncthreads();

    // ---- bconv4: conv -> pool -> 4x4 ----
    {
        uint4 wreg[9];
#pragma unroll
        for (int t = 0; t < 9; ++t) wreg[t] = *(const uint4*)&w4p[(t * 128 + oc) * 4];
        for (int pp = s; pp < 16; pp += 4) {
            int py = pp >> 2, px = pp & 3;
            int cy = py * 2, cx = px * 2;
            int a00 = 0, a01 = 0, a10 = 0, a11 = 0;
#pragma unroll
            for (int rr = 0; rr < 4; ++rr) {
                uint4 rb[4];
#pragma unroll
                for (int j = 0; j < 4; ++j) rb[j] = *(const uint4*)&b3s[((cy + rr) * 10 + cx + j) * 4];
                if (rr <= 2) {
#pragma unroll
                    for (int kx = 0; kx < 3; ++kx) {
                        uint4 wv = wreg[rr * 3 + kx];
                        xp4(a00, rb[kx], wv);
                        xp4(a01, rb[kx + 1], wv);
                    }
                }
                if (rr >= 1) {
#pragma unroll
                    for (int kx = 0; kx < 3; ++kx) {
                        uint4 wv = wreg[(rr - 1) * 3 + kx];
                        xp4(a10, rb[kx], wv);
                        xp4(a11, rb[kx + 1], wv);
                    }
                }
            }
            int m00 = 1152 - 2 * a00, m01 = 1152 - 2 * a01;
            int m10 = 1152 - 2 * a10, m11 = 1152 - 2 * a11;
            int r = max(max(m00, m01), max(m10, m11));
            r = r > 0 ? r : 0;
            h4s[pp * 128 + oc] = (uint16_t)r;
        }
    }
    __syncthreads();

    // ---- npmean16 + binarize -> bxs ----
    npmean_bin_dev<512, 16, 16, 256, 128, 128, 1>((const uint32_t*)h4s, ls, a4, bxs, tid);
    __syncthreads();

    // ---- binary FC: one output per thread ----
    for (int o = tid; o < 512; o += 512) {
        int acc = 0;
#pragma unroll
        for (int k = 0; k < 64; ++k) acc += __popc(bxs[k] ^ fcpT[k * 512 + o]);
        float dot = (float)(2048 - 2 * acc);
        out[(size_t)n * 512 + o] = (dot + bfc[o]) * afc[o];
    }
}

extern "C" void kernel_launch(void* const* d_in, const int* in_sizes, int n_in,
                              void* d_out, int out_size, void* d_ws, size_t ws_size,
                              hipStream_t stream) {
    const float* x   = (const float*)d_in[0];
    const float* w1  = (const float*)d_in[1];
    const float* w2  = (const float*)d_in[2];
    const float* a2  = (const float*)d_in[3];
    const float* w3  = (const float*)d_in[4];
    const float* a3  = (const float*)d_in[5];
    const float* w4  = (const float*)d_in[6];
    const float* a4  = (const float*)d_in[7];
    const float* wfc = (const float*)d_in[8];
    const float* bfc = (const float*)d_in[9];
    const float* afc = (const float*)d_in[10];
    float* out = (float*)d_out;
    char* ws = (char*)d_ws;

    uint32_t* w2f = (uint32_t*)(ws + OFF_W2F);
    uint32_t* w3p = (uint32_t*)(ws + OFF_W3P);
    uint32_t* w4p = (uint32_t*)(ws + OFF_W4P);
    uint32_t* fcp = (uint32_t*)(ws + OFF_FCP);
    int*      zcnt  = (int*)(ws + OFF_STAT + 8192);
    int*      zlist = (int*)(ws + OFF_STAT + 10240);
    float*    csum  = (float*)(ws + OFF_CSUM);
    uint32_t* b1p = (uint32_t*)(ws + OFF_B1P);
    uint16_t* h2  = (uint16_t*)(ws + OFF_H2);
    uint32_t* b2p = (uint32_t*)(ws + OFF_B2P);
    float*    w1p = (float*)(ws + OFF_W1P);

    conv1_csum_pack<<<4096 + 554, 256, 0, stream>>>(
        x, w1, csum, w2, w2f, w3, w4, w3p, w4p, wfc, fcp, zcnt, w1p);
    conv1_bin<<<BATCH * 4, 256, 0, stream>>>(x, w1p, csum, b1p, zcnt, zlist);

    bconv2_mfma<<<BATCH * 6, 256, 0, stream>>>(b1p, (const uint8_t*)w2f, h2, zcnt, zlist);
    npmean144_kernel<<<BATCH, 256, 0, stream>>>(h2, a2, b2p);

    tail_fused<<<BATCH, 512, 0, stream>>>(b2p, w3p, a3, w4p, a4, fcp, bfc, afc, out);
}

// Round 25
// 380.805 us; speedup vs baseline: 1.0424x; 1.0424x over previous
//
#include <hip/hip_runtime.h>
#include <stdint.h>

#define BATCH 512
#define MAXZ 3

typedef int v4i __attribute__((ext_vector_type(4)));
typedef float f2 __attribute__((ext_vector_type(2)));

// ---- workspace layout (bytes) ----
static const size_t OFF_W2F  = 0;          // 50*8*64*16 i8 B-frags = 409600
static const size_t OFF_W3P  = 409600;     // 9*128*4 u32
static const size_t OFF_W4P  = 428032;
static const size_t OFF_FCP  = 446464;     // 64*512 u32
static const size_t OFF_STAT = 577536;     // zcnt@8192; zlist@10240
static const size_t OFF_CSUM = 839680;     // 512*128 f32
static const size_t OFF_B1P  = 1101824;    // 512*784*16
static const size_t OFF_H2   = 7524352;    // 512*144*128*2 u16
static const size_t OFF_B2P  = 26398720;   // 512*144*16
static const size_t OFF_W1P  = 27578368;   // 128*28 f32 (row stride 112B, 16B-aligned)
// end ~27.6 MB

// Numerics model (validated, absmax=0): conv1 = np.einsum f32 SSE2 order;
// means = numpy pairwise-f32 (leaf geometry + adjacent-pair tree); conv2 =
// i8 MFMA with act in {-1,0,+1}; layers 3/4 exact integer xnor-popcount.
//
// bconv2: r19 structure FINAL (104.4us). DO NOT PERTURB.
// Session ladder: 604.7 -> r25 pack-parallel 477.7 -> r26/27 fusion 432.0
// -> r32/33 csum de-spill 393.7 -> r35/36 w1p float4 388.0 -> r37
// packed-f32 einsum 382.1 (BEST). r38 tail_fused 512T REGRESSED (+14.9):
// LDS caps 2 blocks/CU regardless; wider block halves per-thread work,
// idles 384/512 threads in npmean leaf, doubles barrier cost. REVERTED.
// r39 = r37 exact state (tail 256T).

__device__ inline float mulr(float a, float b) {
    float t = a * b;
    asm volatile("" : "+v"(t));
    return t;
}

__device__ inline f2 mkf2(float a, float b) { f2 r; r.x = a; r.y = b; return r; }

__device__ inline void xp4(int& acc, uint4 a, uint4 b) {
    acc += __popc(a.x ^ b.x);
    acc += __popc(a.y ^ b.y);
    acc += __popc(a.z ^ b.z);
    acc += __popc(a.w ^ b.w);
}

// Packed-pair einsum on a register patch array (csum path).
// Component-wise identical op order to the validated scalar einsum25.
__device__ inline float einsum25k(const float* __restrict__ patch,
                                  const float* __restrict__ wr) {
#pragma clang fp contract(off)
    f2 l01 = mkf2(wr[0], wr[1]) * mkf2(patch[0], patch[1]);
    f2 l23 = mkf2(wr[2], wr[3]) * mkf2(patch[2], patch[3]);
#pragma unroll
    for (int t = 1; t < 6; ++t) {
        l01 += mkf2(wr[4 * t + 0], wr[4 * t + 1]) * mkf2(patch[4 * t + 0], patch[4 * t + 1]);
        l23 += mkf2(wr[4 * t + 2], wr[4 * t + 3]) * mkf2(patch[4 * t + 2], patch[4 * t + 3]);
    }
    float acc = (l01.x + l01.y) + (l23.x + l23.y);
    acc += wr[24] * patch[24];
    return acc > 0.f ? acc : 0.f;
}

// Packed-pair einsum on 25 named scalars + float4 weight loads from the
// padded 16B-aligned w1p row (bin path). Component-wise identical op
// order => bit-exact.
__device__ inline float einsum25pk(
    float p0, float p1, float p2, float p3, float p4,
    float p5, float p6, float p7, float p8, float p9,
    float p10, float p11, float p12, float p13, float p14,
    float p15, float p16, float p17, float p18, float p19,
    float p20, float p21, float p22, float p23, float p24,
    const float* __restrict__ wr) {
#pragma clang fp contract(off)
    float4 wa = *(const float4*)(wr + 0);
    float4 wb = *(const float4*)(wr + 4);
    float4 wc = *(const float4*)(wr + 8);
    float4 wd = *(const float4*)(wr + 12);
    float4 we = *(const float4*)(wr + 16);
    float4 wf = *(const float4*)(wr + 20);
    float w24 = wr[24];
    f2 l01 = mkf2(wa.x, wa.y) * mkf2(p0, p1);
    f2 l23 = mkf2(wa.z, wa.w) * mkf2(p2, p3);
    l01 += mkf2(wb.x, wb.y) * mkf2(p4, p5);
    l23 += mkf2(wb.z, wb.w) * mkf2(p6, p7);
    l01 += mkf2(wc.x, wc.y) * mkf2(p8, p9);
    l23 += mkf2(wc.z, wc.w) * mkf2(p10, p11);
    l01 += mkf2(wd.x, wd.y) * mkf2(p12, p13);
    l23 += mkf2(wd.z, wd.w) * mkf2(p14, p15);
    l01 += mkf2(we.x, we.y) * mkf2(p16, p17);
    l23 += mkf2(we.z, we.w) * mkf2(p18, p19);
    l01 += mkf2(wf.x, wf.y) * mkf2(p20, p21);
    l23 += mkf2(wf.z, wf.w) * mkf2(p22, p23);
    float acc = (l01.x + l01.y) + (l23.x + l23.y);
    acc += w24 * p24;
    return acc > 0.f ? acc : 0.f;
}

// ---- shared npmean+binarize math on LDS-resident u16 counts ----
template <int NT, int NPOS, int NLEAF, int CHUNK, int L0, int L1, int MODE>
__device__ inline void npmean_bin_dev(const uint32_t* sh, float* ls,
                                      const float* __restrict__ alpha,
                                      uint32_t* dst, int tid) {
    const int NTOT = NPOS * 128;
    if (tid < NLEAF) {
        int j0 = CHUNK * (tid >> 1) + ((tid & 1) ? L0 : 0);
        int len = (tid & 1) ? L1 : L0;
        float r[8];
#pragma unroll
        for (int k = 0; k < 8; ++k) {
            int j = j0 + k;
            int c = j / NPOS, p = j - c * NPOS;
            int e = p * 128 + c;
            uint32_t w = sh[e >> 1];
            float fv = (float)((e & 1) ? (w >> 16) : (w & 0xffffu));
            r[k] = mulr(alpha[c], fv);
        }
        int i = 8;
        int lim = len - (len % 8);
        for (; i < lim; i += 8) {
#pragma unroll
            for (int k = 0; k < 8; ++k) {
                int j = j0 + i + k;
                int c = j / NPOS, p = j - c * NPOS;
                int e = p * 128 + c;
                uint32_t w = sh[e >> 1];
                float fv = (float)((e & 1) ? (w >> 16) : (w & 0xffffu));
                r[k] += mulr(alpha[c], fv);
            }
        }
        float res = ((r[0] + r[1]) + (r[2] + r[3])) + ((r[4] + r[5]) + (r[6] + r[7]));
        for (; i < len; ++i) {
            int j = j0 + i;
            int c = j / NPOS, p = j - c * NPOS;
            int e = p * 128 + c;
            uint32_t w = sh[e >> 1];
            float fv = (float)((e & 1) ? (w >> 16) : (w & 0xffffu));
            res += mulr(alpha[c], fv);
        }
        ls[tid] = res;
    }
    __syncthreads();
    int src = 0, cnt = NLEAF;
    while (cnt > 1) {
        int dst2 = src + cnt;
        for (int i = tid; i < cnt / 2; i += NT) ls[dst2 + i] = ls[src + 2 * i] + ls[src + 2 * i + 1];
        __syncthreads();
        src = dst2; cnt >>= 1;
    }
    float mean = ls[src] / (float)NTOT;
    if (MODE == 0) {
        for (int widx = tid; widx < NPOS * 4; widx += NT) {
            int w = widx & 3;
            uint32_t bits = 0;
#pragma unroll
            for (int i = 0; i < 32; i += 2) {
                uint32_t pw = sh[widx * 16 + (i >> 1)];
                float v0 = mulr(alpha[w * 32 + i], (float)(pw & 0xffffu));
                float v1 = mulr(alpha[w * 32 + i + 1], (float)(pw >> 16));
                bits |= (v0 > mean ? 1u : 0u) << i;
                bits |= (v1 > mean ? 1u : 0u) << (i + 1);
            }
            dst[widx] = bits;
        }
    } else {
        if (tid < 64) {
            int w = tid;
            uint32_t bits = 0;
#pragma unroll
            for (int i = 0; i < 32; ++i) {
                int f = w * 32 + i;
                int c = f >> 4, sp = f & 15;
                int e = sp * 128 + c;
                uint32_t pw = sh[e >> 1];
                float v = mulr(alpha[c], (float)((e & 1) ? (pw >> 16) : (pw & 0xffffu)));
                bits |= (v > mean ? 1u : 0u) << i;
            }
            dst[w] = bits;
        }
    }
}

// ---------------- conv1 channel sums + (absorbed) weight packing ----------
// launch_bounds(256,2) => VGPR ceiling 256: wreg[4][25]+patch[25] resident.
__global__ __launch_bounds__(256, 2) void conv1_csum_pack(
    const float* __restrict__ x, const float* __restrict__ w1,
    float* __restrict__ csum,
    const float* __restrict__ w2, uint32_t* __restrict__ b2f,
    const float* __restrict__ w3, const float* __restrict__ w4,
    uint32_t* __restrict__ w3p, uint32_t* __restrict__ w4p,
    const float* __restrict__ wfc, uint32_t* __restrict__ fcp,
    int* __restrict__ zcnt, float* __restrict__ w1p) {
    __shared__ float img[32 * 36];
    int blk = blockIdx.x;
    int tid = threadIdx.x;
    if (blk >= 4096) {
        int idx = (blk - 4096) * 256 + tid;
        if (idx < 102400) {
            int d = idx;
            int j4 = d & 3;
            int lane = (d >> 2) & 63;
            int ok = d >> 8;
            int octile = ok & 7, kstep = ok >> 3;
            int oc = octile * 16 + (lane & 15);
            uint32_t dv = 0;
#pragma unroll
            for (int jj = 0; jj < 4; ++jj) {
                int j = j4 * 4 + jj;
                int k = kstep * 64 + (lane >> 4) * 16 + j;
                int tap = k >> 7, ch = k & 127;
                uint32_t byte = (w2[(size_t)(oc * 128 + ch) * 25 + tap] > 0.f) ? 0x01u : 0xFFu;
                dv |= byte << (8 * jj);
            }
            b2f[d] = dv;
        } else if (idx < 104704) {
            int id2 = idx - 102400;
            const float* w = (id2 < 1152) ? w3 : w4;
            uint32_t* wp = (id2 < 1152) ? w3p : w4p;
            int id3 = (id2 < 1152) ? id2 : id2 - 1152;
            int oc = id3 / 9, t = id3 - oc * 9;
            uint32_t words[4] = {0u, 0u, 0u, 0u};
            for (int ic = 0; ic < 128; ++ic) {
                float v = w[(size_t)(oc * 128 + ic) * 9 + t];
                if (v > 0.f) words[ic >> 5] |= 1u << (ic & 31);
            }
#pragma unroll
            for (int k = 0; k < 4; ++k) wp[((size_t)t * 128 + oc) * 4 + k] = words[k];
        } else if (idx < 137472) {
            int id2 = idx - 104704;
            int o = id2 >> 6, k = id2 & 63;
            uint32_t bits = 0;
#pragma unroll
            for (int i = 0; i < 32; ++i)
                bits |= (wfc[(size_t)o * 2048 + k * 32 + i] > 0.f ? 1u : 0u) << i;
            fcp[k * 512 + o] = bits;
        } else if (idx < 137984) {
            zcnt[idx - 137472] = 0;
        } else if (idx < 141568) {
            // w1 -> padded w1p[128][28]: row stride 112B (16B-aligned)
            int e = idx - 137984;
            int c = e / 28, t = e - c * 28;
            w1p[e] = (t < 25) ? w1[c * 25 + t] : 0.f;
        }
        return;
    }
    int n = blk >> 3, g = blk & 7;
    for (int i = tid; i < 1024; i += 256) {
        int y = i >> 5, xx = i & 31;
        img[y * 36 + xx] = x[(size_t)n * 1024 + i];
    }
    __syncthreads();
    int wave = tid >> 6, lane = tid & 63;
    int seg = lane >> 3, k = lane & 7;
    int soff = seg * 96 + (seg >= 4 ? 8 : 0);
    int strips = ((seg & 3) == 3) ? 13 : 12;
    int c0 = g * 16 + wave * 4;
    float wreg[4][25];
#pragma unroll
    for (int it = 0; it < 4; ++it)
#pragma unroll
        for (int t = 0; t < 25; ++t) wreg[it][t] = w1[(c0 + it) * 25 + t];
    float racc[4];
    for (int i = 0; i < strips; ++i) {
        int p = soff + 8 * i + k;
        int y = p / 28, xx = p - y * 28;
        const float* ib = &img[y * 36 + xx];
        float patch[25];
#pragma unroll
        for (int ky = 0; ky < 5; ++ky)
#pragma unroll
            for (int kx = 0; kx < 5; ++kx)
                patch[ky * 5 + kx] = ib[ky * 36 + kx];
#pragma unroll
        for (int it = 0; it < 4; ++it) {
            float h = einsum25k(patch, wreg[it]);
            racc[it] = (i == 0) ? h : racc[it] + h;
        }
    }
#pragma unroll
    for (int it = 0; it < 4; ++it) {
        float r = racc[it];
        r = r + __shfl_xor(r, 1);
        r = r + __shfl_xor(r, 2);
        r = r + __shfl_xor(r, 4);   // leaf sum
        r = r + __shfl_xor(r, 8);
        r = r + __shfl_xor(r, 16);
        r = r + __shfl_xor(r, 32);  // channel sum
        if (lane == 0) csum[n * 128 + c0 + it] = r;
    }
}

// ---------------- conv1 binarize + pack (tree folded in); grid (n, q) -----
// Weights from padded w1p rows via float4; packed-f32 einsum.
__global__ __launch_bounds__(256) void conv1_bin(
    const float* __restrict__ x, const float* __restrict__ w1p,
    const float* __restrict__ csum, uint32_t* __restrict__ b1p,
    int* __restrict__ zcnt, int* __restrict__ zlist) {
    __shared__ float img[32 * 36];
    __shared__ float tree[256];
    int blk = blockIdx.x;
    int n = blk >> 2, q = blk & 3;
    int tid = threadIdx.x;
    for (int i = tid; i < 1024; i += 256) {
        int y = i >> 5, xx = i & 31;
        img[y * 36 + xx] = x[(size_t)n * 1024 + i];
    }
    if (tid < 128) tree[tid] = csum[n * 128 + tid];
    __syncthreads();
    int src = 0, cnt = 128;
    while (cnt > 1) {
        int dst = src + cnt;
        for (int i = tid; i < cnt / 2; i += 256) tree[dst + i] = tree[src + 2 * i] + tree[src + 2 * i + 1];
        __syncthreads();
        src = dst; cnt >>= 1;
    }
    float mean = tree[src] / 100352.0f;
    int p = q * 256 + tid;
    if (p < 784) {
        int y = p / 28, xx = p - y * 28;
        const float* ib = &img[y * 36 + xx];
        float p0  = ib[0],   p1  = ib[1],   p2  = ib[2],   p3  = ib[3],   p4  = ib[4];
        float p5  = ib[36],  p6  = ib[37],  p7  = ib[38],  p8  = ib[39],  p9  = ib[40];
        float p10 = ib[72],  p11 = ib[73],  p12 = ib[74],  p13 = ib[75],  p14 = ib[76];
        float p15 = ib[108], p16 = ib[109], p17 = ib[110], p18 = ib[111], p19 = ib[112];
        float p20 = ib[144], p21 = ib[145], p22 = ib[146], p23 = ib[147], p24 = ib[148];
        uint32_t words[4] = {0u, 0u, 0u, 0u};
#pragma unroll 2
        for (int c = 0; c < 128; ++c) {
            float h = einsum25pk(p0, p1, p2, p3, p4, p5, p6, p7, p8, p9,
                                 p10, p11, p12, p13, p14, p15, p16, p17, p18, p19,
                                 p20, p21, p22, p23, p24, w1p + c * 28);
            if (h > mean) words[c >> 5] |= 1u << (c & 31);
            else if (h == mean) {
                int kz = atomicAdd(&zcnt[n], 1);
                if (kz < MAXZ) zlist[n * MAXZ + kz] = p * 128 + c;
            }
        }
#pragma unroll
        for (int k = 0; k < 4; ++k) b1p[((size_t)n * 784 + p) * 4 + k] = words[k];
    }
}

// ---------------- bconv2 via i8 MFMA (r19 FINAL — do not perturb) ----------
__global__ __launch_bounds__(256) void bconv2_mfma(
    const uint32_t* __restrict__ b1p, const uint8_t* __restrict__ b2f,
    uint16_t* __restrict__ rout, const int* __restrict__ zcnt,
    const int* __restrict__ zlist) {
    __shared__ __align__(16) uint32_t acts32[7168];   // 8*28*128 i8 = 28672 B
    uint8_t* acts = (uint8_t*)acts32;
    int blk = blockIdx.x;
    int n = blk / 6, r = blk - n * 6;
    int tid = threadIdx.x;
    const uint32_t* bsrc = b1p + ((size_t)n * 784 + 4 * r * 28) * 4;
    for (int d = tid; d < 7168; d += 256) {
        int pos = d >> 5;
        int nibidx = d & 31;
        uint32_t word = bsrc[pos * 4 + (nibidx >> 3)];
        uint32_t nib = (word >> ((nibidx & 7) * 4)) & 0xF;
        uint32_t spread = (nib * 0x00204081u) & 0x01010101u;
        int dsw = d ^ ((pos & 7) << 2);                // swizzled dword index
        acts32[dsw] = ~(spread * 0xFEu);
    }
    __syncthreads();
    if (tid == 0) {
        int nz = zcnt[n]; nz = nz > MAXZ ? MAXZ : nz;
        for (int i = 0; i < nz; ++i) {
            int e = zlist[n * MAXZ + i];
            int p = e >> 7, zc = e & 127;
            int zy = p / 28, zx = p - zy * 28;
            int ry = zy - 4 * r;
            if (ry >= 0 && ry < 8) {
                int ba = ((ry * 28 + zx) * 128 + zc);
                ba ^= ((ba >> 7) & 7) << 4;
                acts[ba] = 0;
            }
        }
    }
    __syncthreads();

    int lane = tid & 63, w = tid >> 6;
    int rr = w >> 1, oh = w & 1;
    int ml = lane & 15, khi = lane >> 4;
    int pairl = ml >> 2, dy = (ml >> 1) & 1, dx = ml & 1;
    int abase[3];
#pragma unroll
    for (int t = 0; t < 3; ++t) {
        int px = 2 * (4 * t + pairl) + dx;
        abase[t] = ((dy + 2 * rr) * 28 + px) * 128 + khi * 16;
    }
    const uint8_t* bp = b2f + (size_t)(oh * 4096 + lane * 16);
    v4i c[3][4] = {};
#pragma unroll 2
    for (int kstep = 0; kstep < 50; ++kstep) {
        int tap = kstep >> 1;
        int ky = tap / 5, kx = tap - ky * 5;
        int koff = (ky * 28 + kx) * 128 + (kstep & 1) * 64;
        int a0a = abase[0] + koff; a0a ^= ((a0a >> 7) & 7) << 4;
        int a1a = abase[1] + koff; a1a ^= ((a1a >> 7) & 7) << 4;
        int a2a = abase[2] + koff; a2a ^= ((a2a >> 7) & 7) << 4;
        v4i a0 = *(const v4i*)(acts + a0a);
        v4i a1 = *(const v4i*)(acts + a1a);
        v4i a2 = *(const v4i*)(acts + a2a);
        const uint8_t* bk = bp + kstep * 8192;
#pragma unroll
        for (int o = 0; o < 4; ++o) {
            v4i b = *(const v4i*)(bk + o * 1024);
            c[0][o] = __builtin_amdgcn_mfma_i32_16x16x64_i8(a0, b, c[0][o], 0, 0, 0);
            c[1][o] = __builtin_amdgcn_mfma_i32_16x16x64_i8(a1, b, c[1][o], 0, 0, 0);
            c[2][o] = __builtin_amdgcn_mfma_i32_16x16x64_i8(a2, b, c[2][o], 0, 0, 0);
        }
    }
    uint16_t* outb = rout + ((size_t)n * 144 + (2 * r + rr) * 12) * 128;
#pragma unroll
    for (int t = 0; t < 3; ++t) {
#pragma unroll
        for (int o = 0; o < 4; ++o) {
            v4i cc = c[t][o];
            int m = max(max(cc.x, cc.y), max(cc.z, cc.w));
            m = m > 0 ? m : 0;
            outb[(4 * t + khi) * 128 + (4 * oh + o) * 16 + ml] = (uint16_t)m;
        }
    }
}

// ---------------- npmean144: h2 -> b2p ----------------
__global__ __launch_bounds__(256) void npmean144_kernel(
    const uint16_t* __restrict__ rbuf, const float* __restrict__ alpha,
    uint32_t* __restrict__ bp) {
    __shared__ uint32_t sh[144 * 64];
    __shared__ float ls[2 * 256];
    int n = blockIdx.x, tid = threadIdx.x;
    const uint32_t* rb32 = (const uint32_t*)(rbuf + (size_t)n * 144 * 128);
    for (int i = tid; i < 144 * 64; i += 256) sh[i] = rb32[i];
    __syncthreads();
    npmean_bin_dev<256, 144, 256, 144, 72, 72, 0>(sh, ls, alpha, bp + (size_t)n * 576, tid);
}

// ---------------- tail_fused: bconv3+npmean100+bconv4+npmean16+fc ---------
// 256 threads (r37 form — r38's 512T regressed: LDS caps 2 blocks/CU,
// wider block just idles lanes and doubles barrier cost).
__global__ __launch_bounds__(256) void tail_fused(
    const uint32_t* __restrict__ b2p,
    const uint32_t* __restrict__ w3p, const float* __restrict__ a3,
    const uint32_t* __restrict__ w4p, const float* __restrict__ a4,
    const uint32_t* __restrict__ fcpT, const float* __restrict__ bfc,
    const float* __restrict__ afc, float* __restrict__ out) {
    __shared__ __align__(16) uint32_t act[576];
    __shared__ __align__(16) uint16_t h3s[100 * 128];   // 25.6 KB
    __shared__ float ls[2 * 128];
    __shared__ __align__(16) uint32_t b3s[400];
    __shared__ __align__(16) uint16_t h4s[16 * 128];
    __shared__ uint32_t bxs[64];
    int n = blockIdx.x, tid = threadIdx.x;
    int oc = tid & 127, s = tid >> 7;

    // ---- bconv3: 12x12 -> 10x10 ----
    const uint32_t* src = b2p + (size_t)n * 576;
    for (int i = tid; i < 576; i += 256) act[i] = src[i];
    {
        uint4 wreg[9];
#pragma unroll
        for (int t = 0; t < 9; ++t) wreg[t] = *(const uint4*)&w3p[(t * 128 + oc) * 4];
        __syncthreads();
        for (int pp = s; pp < 100; pp += 2) {
            int py = pp / 10, px = pp - py * 10;
            int acc = 0;
#pragma unroll
            for (int rr = 0; rr < 3; ++rr)
#pragma unroll
                for (int kx = 0; kx < 3; ++kx)
                    xp4(acc, *(const uint4*)&act[((py + rr) * 12 + px + kx) * 4], wreg[rr * 3 + kx]);
            int r = 1152 - 2 * acc;
            r = r > 0 ? r : 0;
            h3s[pp * 128 + oc] = (uint16_t)r;
        }
    }
    __syncthreads();

    // ---- npmean100 + binarize -> b3s ----
    npmean_bin_dev<256, 100, 128, 200, 96, 104, 0>((const uint32_t*)h3s, ls, a3, b3s, tid);
    __syncthreads();

    // ---- bconv4: conv -> pool -> 4x4 ----
    {
        uint4 wreg[9];
#pragma unroll
        for (int t = 0; t < 9; ++t) wreg[t] = *(const uint4*)&w4p[(t * 128 + oc) * 4];
        for (int pp = s; pp < 16; pp += 2) {
            int py = pp >> 2, px = pp & 3;
            int cy = py * 2, cx = px * 2;
            int a00 = 0, a01 = 0, a10 = 0, a11 = 0;
#pragma unroll
            for (int rr = 0; rr < 4; ++rr) {
                uint4 rb[4];
#pragma unroll
                for (int j = 0; j < 4; ++j) rb[j] = *(const uint4*)&b3s[((cy + rr) * 10 + cx + j) * 4];
                if (rr <= 2) {
#pragma unroll
                    for (int kx = 0; kx < 3; ++kx) {
                        uint4 wv = wreg[rr * 3 + kx];
                        xp4(a00, rb[kx], wv);
                        xp4(a01, rb[kx + 1], wv);
                    }
                }
                if (rr >= 1) {
#pragma unroll
                    for (int kx = 0; kx < 3; ++kx) {
                        uint4 wv = wreg[(rr - 1) * 3 + kx];
                        xp4(a10, rb[kx], wv);
                        xp4(a11, rb[kx + 1], wv);
                    }
                }
            }
            int m00 = 1152 - 2 * a00, m01 = 1152 - 2 * a01;
            int m10 = 1152 - 2 * a10, m11 = 1152 - 2 * a11;
            int r = max(max(m00, m01), max(m10, m11));
            r = r > 0 ? r : 0;
            h4s[pp * 128 + oc] = (uint16_t)r;
        }
    }
    __syncthreads();

    // ---- npmean16 + binarize -> bxs ----
    npmean_bin_dev<256, 16, 16, 256, 128, 128, 1>((const uint32_t*)h4s, ls, a4, bxs, tid);
    __syncthreads();

    // ---- binary FC ----
    for (int o = tid; o < 512; o += 256) {
        int acc = 0;
#pragma unroll
        for (int k = 0; k < 64; ++k) acc += __popc(bxs[k] ^ fcpT[k * 512 + o]);
        float dot = (float)(2048 - 2 * acc);
        out[(size_t)n * 512 + o] = (dot + bfc[o]) * afc[o];
    }
}

extern "C" void kernel_launch(void* const* d_in, const int* in_sizes, int n_in,
                              void* d_out, int out_size, void* d_ws, size_t ws_size,
                              hipStream_t stream) {
    const float* x   = (const float*)d_in[0];
    const float* w1  = (const float*)d_in[1];
    const float* w2  = (const float*)d_in[2];
    const float* a2  = (const float*)d_in[3];
    const float* w3  = (const float*)d_in[4];
    const float* a3  = (const float*)d_in[5];
    const float* w4  = (const float*)d_in[6];
    const float* a4  = (const float*)d_in[7];
    const float* wfc = (const float*)d_in[8];
    const float* bfc = (const float*)d_in[9];
    const float* afc = (const float*)d_in[10];
    float* out = (float*)d_out;
    char* ws = (char*)d_ws;

    uint32_t* w2f = (uint32_t*)(ws + OFF_W2F);
    uint32_t* w3p = (uint32_t*)(ws + OFF_W3P);
    uint32_t* w4p = (uint32_t*)(ws + OFF_W4P);
    uint32_t* fcp = (uint32_t*)(ws + OFF_FCP);
    int*      zcnt  = (int*)(ws + OFF_STAT + 8192);
    int*      zlist = (int*)(ws + OFF_STAT + 10240);
    float*    csum  = (float*)(ws + OFF_CSUM);
    uint32_t* b1p = (uint32_t*)(ws + OFF_B1P);
    uint16_t* h2  = (uint16_t*)(ws + OFF_H2);
    uint32_t* b2p = (uint32_t*)(ws + OFF_B2P);
    float*    w1p = (float*)(ws + OFF_W1P);

    conv1_csum_pack<<<4096 + 554, 256, 0, stream>>>(
        x, w1, csum, w2, w2f, w3, w4, w3p, w4p, wfc, fcp, zcnt, w1p);
    conv1_bin<<<BATCH * 4, 256, 0, stream>>>(x, w1p, csum, b1p, zcnt, zlist);

    bconv2_mfma<<<BATCH * 6, 256, 0, stream>>>(b1p, (const uint8_t*)w2f, h2, zcnt, zlist);
    npmean144_kernel<<<BATCH, 256, 0, stream>>>(h2, a2, b2p);

    tail_fused<<<BATCH, 256, 0, stream>>>(b2p, w3p, a3, w4p, a4, fcp, bfc, afc, out);
}